// Round 7
// baseline (185.597 us; speedup 1.0000x reference)
//
#include <hip/hip_runtime.h>
#include <cstdint>

#define NN    1024
#define MM    32
#define NEDGE 32240
#define MROWS 64480   // 2*NEDGE

typedef unsigned short ushort_t;

typedef __bf16 bf16x8 __attribute__((ext_vector_type(8)));
typedef float  floatx4 __attribute__((ext_vector_type(4)));

__device__ __forceinline__ float b2f(ushort_t u) {
    union { unsigned int i; float f; } v; v.i = ((unsigned int)u) << 16; return v.f;
}
__device__ __forceinline__ ushort_t f2b(float f) {
    unsigned int u = __builtin_bit_cast(unsigned int, f);
    u = (u + 0x7FFFu + ((u >> 16) & 1u)) >> 16;
    return (ushort_t)u;
}
// K(i): number of edges before node i
__device__ __forceinline__ int edge_base(int i) {
    return (i <= MM) ? ((i * (i - 1)) >> 1) : (496 + (i - MM) * MM);
}
// edge id e -> (dest i, src j)   [validated round 3]
__device__ __forceinline__ void edge_ij(int e, int& i, int& j) {
    if (e < 496) {
        i = (int)((1.0f + sqrtf(8.0f * (float)e + 1.0f)) * 0.5f);
        while (((i * (i - 1)) >> 1) > e) --i;
        while (((i * (i + 1)) >> 1) <= e) ++i;
        j = e - ((i * (i - 1)) >> 1);
    } else {
        int q = e - 496;
        i = MM + (q >> 5);
        j = i - MM + (q & 31);
    }
}

// ---------------- pack: weight transpose fp32->bf16 + nodes bf16 ----------------
__global__ void k_pack(const float* an1, const float* an2, const float* ae1,
                       const float* ae2, const float* le1, const float* le2,
                       const float* ln1, const float* ln2, const float* nodes,
                       ushort_t* pan1, ushort_t* pan2, ushort_t* pae1, ushort_t* pae2,
                       ushort_t* ple1, ushort_t* ple2, ushort_t* pln1, ushort_t* pln2,
                       ushort_t* nodesb) {
    int idx = blockIdx.x * 256 + threadIdx.x;   // grid 736*256 = 188416 exactly
    if (idx < 155648) {
        const float* s; ushort_t* d; int K, N, off;
        if (idx < 40960)       { s = an1; d = pan1; K = 160; N = 256; off = idx;          }
        else if (idx < 73728)  { s = an2; d = pan2; K = 256; N = 128; off = idx - 40960;  }
        else if (idx < 86016)  { s = ae1; d = pae1; K = 96;  N = 128; off = idx - 73728;  }
        else if (idx < 94208)  { s = ae2; d = pae2; K = 128; N = 64;  off = idx - 86016;  }
        else if (idx < 103424) { s = le1; d = ple1; K = 96;  N = 96;  off = idx - 94208;  }
        else if (idx < 106496) { s = le2; d = ple2; K = 96;  N = 32;  off = idx - 103424; }
        else if (idx < 143360) { s = ln1; d = pln1; K = 192; N = 192; off = idx - 106496; }
        else                   { s = ln2; d = pln2; K = 192; N = 64;  off = idx - 143360; }
        int n = off / K, k = off - n * K;
        d[off] = f2b(s[k * N + n]);
    } else {
        int i4 = idx - 155648;                 // 0..32767
        float4 v = ((const float4*)nodes)[i4];
        uint2 o;
        o.x = (unsigned)f2b(v.x) | ((unsigned)f2b(v.y) << 16);
        o.y = (unsigned)f2b(v.z) | ((unsigned)f2b(v.w) << 16);
        ((uint2*)nodesb)[i4] = o;
    }
}

// ---------------- agg: node branch (gather + an1 + an2 -> hn) | edge branch (-> he) ----------------
// 256 threads = 4 waves = 4 col-groups; each wave loops both 16-row subtiles (s).
#define NODE_BLKS 384
#define EDGE_BLKS 128
__global__ __launch_bounds__(256, 2) void k_agg(
        const ushort_t* __restrict__ nodesb, const float* __restrict__ edges,
        const ushort_t* __restrict__ pan1, const float* __restrict__ ban1,
        const ushort_t* __restrict__ pan2, const float* __restrict__ ban2,
        const ushort_t* __restrict__ pae1, const float* __restrict__ bae1,
        const ushort_t* __restrict__ pae2, const float* __restrict__ bae2,
        ushort_t* __restrict__ hn, ushort_t* __restrict__ he) {
    __shared__ alignas(16) ushort_t L1[32 * 168];   // node: X tile (pitch 168) / edge: pairs (pitch 104)
    __shared__ alignas(16) ushort_t L2[32 * 264];   // node: H1n (pitch 264) / edge: H1e (pitch 136)
    const int tid = threadIdx.x;
    const int w = tid >> 6, l = tid & 63, lrow = l & 15, lq = l >> 4;
    floatx4 zero = {0.f, 0.f, 0.f, 0.f};

    if (blockIdx.x < NODE_BLKS) {
        // B-frags: an1 cols w*64..+63 (NT=4, KT=5); an2 cols w*32..+31 (NT=2, KT=8)
        bf16x8 b1[5][4]; float v1[4];
#pragma unroll
        for (int kt = 0; kt < 5; ++kt)
#pragma unroll
            for (int nt = 0; nt < 4; ++nt)
                b1[kt][nt] = *(const bf16x8*)(pan1 + (size_t)(w * 64 + nt * 16 + lrow) * 160 + kt * 32 + lq * 8);
#pragma unroll
        for (int nt = 0; nt < 4; ++nt) v1[nt] = ban1[w * 64 + nt * 16 + lrow];
        bf16x8 b2[8][2]; float v2[2];
#pragma unroll
        for (int kt = 0; kt < 8; ++kt)
#pragma unroll
            for (int nt = 0; nt < 2; ++nt)
                b2[kt][nt] = *(const bf16x8*)(pan2 + (size_t)(w * 32 + nt * 16 + lrow) * 256 + kt * 32 + lq * 8);
#pragma unroll
        for (int nt = 0; nt < 2; ++nt) v2[nt] = ban2[w * 32 + nt * 16 + lrow];

        for (int mt = blockIdx.x; mt < 2015; mt += NODE_BLKS) {
            // gather: wave w rows w*8..w*8+7; contiguous segments per row
#pragma unroll
            for (int k = 0; k < 8; ++k) {
                int rr = w * 8 + k;
                int r = mt * 32 + rr;
                int b = (r >= NEDGE) ? 1 : 0;
                int e = r - b * NEDGE;
                int i, j; edge_ij(e, i, j);
                ushort_t* xr = L1 + rr * 168;
                const unsigned* nj = (const unsigned*)(nodesb + (size_t)(b * NN + j) * 64);
                const unsigned* ni = (const unsigned*)(nodesb + (size_t)(b * NN + i) * 64);
                if (l < 32) { ((unsigned*)xr)[l] = nj[l]; ((unsigned*)xr)[48 + l] = ni[l]; }
                else        xr[64 + (l - 32)] = f2b(edges[(size_t)r * 32 + (l - 32)]);
            }
            __syncthreads();

            // an1: 160 -> 256
            floatx4 acc[2][4];
#pragma unroll
            for (int s = 0; s < 2; ++s)
#pragma unroll
                for (int nt = 0; nt < 4; ++nt) acc[s][nt] = zero;
#pragma unroll
            for (int s = 0; s < 2; ++s)
#pragma unroll
                for (int kt = 0; kt < 5; ++kt) {
                    bf16x8 a = *(const bf16x8*)&L1[(s * 16 + lrow) * 168 + kt * 32 + lq * 8];
#pragma unroll
                    for (int nt = 0; nt < 4; ++nt)
                        acc[s][nt] = __builtin_amdgcn_mfma_f32_16x16x32_bf16(a, b1[kt][nt], acc[s][nt], 0, 0, 0);
                }
#pragma unroll
            for (int s = 0; s < 2; ++s)
#pragma unroll
                for (int nt = 0; nt < 4; ++nt) {
                    int col = w * 64 + nt * 16 + lrow;
#pragma unroll
                    for (int r_ = 0; r_ < 4; ++r_)
                        L2[(s * 16 + lq * 4 + r_) * 264 + col] = f2b(fmaxf(acc[s][nt][r_] + v1[nt], 0.f));
                }
            __syncthreads();

            // an2: 256 -> 128
            floatx4 a2[2][2];
#pragma unroll
            for (int s = 0; s < 2; ++s) { a2[s][0] = zero; a2[s][1] = zero; }
#pragma unroll
            for (int s = 0; s < 2; ++s)
#pragma unroll
                for (int kt = 0; kt < 8; ++kt) {
                    bf16x8 a = *(const bf16x8*)&L2[(s * 16 + lrow) * 264 + kt * 32 + lq * 8];
#pragma unroll
                    for (int nt = 0; nt < 2; ++nt)
                        a2[s][nt] = __builtin_amdgcn_mfma_f32_16x16x32_bf16(a, b2[kt][nt], a2[s][nt], 0, 0, 0);
                }
#pragma unroll
            for (int s = 0; s < 2; ++s)
#pragma unroll
                for (int nt = 0; nt < 2; ++nt) {
                    int col = w * 32 + nt * 16 + lrow;
#pragma unroll
                    for (int r_ = 0; r_ < 4; ++r_)
                        hn[(size_t)(mt * 32 + s * 16 + lq * 4 + r_) * 128 + col] = f2b(fmaxf(a2[s][nt][r_] + v2[nt], 0.f));
                }
            __syncthreads();
        }
    } else {
        // edge branch: ae1 cols w*32..+31 (NT=2, KT=3); ae2 cols w*16..+15 (NT=1, KT=4)
        bf16x8 e1[3][2]; float v1[2];
#pragma unroll
        for (int kt = 0; kt < 3; ++kt)
#pragma unroll
            for (int nt = 0; nt < 2; ++nt)
                e1[kt][nt] = *(const bf16x8*)(pae1 + (size_t)(w * 32 + nt * 16 + lrow) * 96 + kt * 32 + lq * 8);
#pragma unroll
        for (int nt = 0; nt < 2; ++nt) v1[nt] = bae1[w * 32 + nt * 16 + lrow];
        bf16x8 e2[4];
#pragma unroll
        for (int kt = 0; kt < 4; ++kt)
            e2[kt] = *(const bf16x8*)(pae2 + (size_t)(w * 16 + lrow) * 128 + kt * 32 + lq * 8);
        float v2 = bae2[w * 16 + lrow];

        for (int mt = blockIdx.x - NODE_BLKS; mt < 2015; mt += EDGE_BLKS) {
#pragma unroll
            for (int k = 0; k < 8; ++k) {
                int rr = w * 8 + k;
                int r = mt * 32 + rr;
                int b = (r >= NEDGE) ? 1 : 0;
                int e = r - b * NEDGE;
                int i, j; edge_ij(e, i, j);
                (void)i;
                ushort_t* xr = L1 + rr * 104;
                const unsigned* nj = (const unsigned*)(nodesb + (size_t)(b * NN + j) * 64);
                if (l < 32) ((unsigned*)xr)[l] = nj[l];
                else        xr[64 + (l - 32)] = f2b(edges[(size_t)r * 32 + (l - 32)]);
            }
            __syncthreads();

            floatx4 acc[2][2];
#pragma unroll
            for (int s = 0; s < 2; ++s) { acc[s][0] = zero; acc[s][1] = zero; }
#pragma unroll
            for (int s = 0; s < 2; ++s)
#pragma unroll
                for (int kt = 0; kt < 3; ++kt) {
                    bf16x8 a = *(const bf16x8*)&L1[(s * 16 + lrow) * 104 + kt * 32 + lq * 8];
#pragma unroll
                    for (int nt = 0; nt < 2; ++nt)
                        acc[s][nt] = __builtin_amdgcn_mfma_f32_16x16x32_bf16(a, e1[kt][nt], acc[s][nt], 0, 0, 0);
                }
#pragma unroll
            for (int s = 0; s < 2; ++s)
#pragma unroll
                for (int nt = 0; nt < 2; ++nt) {
                    int col = w * 32 + nt * 16 + lrow;
#pragma unroll
                    for (int r_ = 0; r_ < 4; ++r_)
                        L2[(s * 16 + lq * 4 + r_) * 136 + col] = f2b(fmaxf(acc[s][nt][r_] + v1[nt], 0.f));
                }
            __syncthreads();

            floatx4 a2[2] = {zero, zero};
#pragma unroll
            for (int s = 0; s < 2; ++s)
#pragma unroll
                for (int kt = 0; kt < 4; ++kt) {
                    bf16x8 a = *(const bf16x8*)&L2[(s * 16 + lrow) * 136 + kt * 32 + lq * 8];
                    a2[s] = __builtin_amdgcn_mfma_f32_16x16x32_bf16(a, e2[kt], a2[s], 0, 0, 0);
                }
#pragma unroll
            for (int s = 0; s < 2; ++s) {
                int col = w * 16 + lrow;
#pragma unroll
                for (int r_ = 0; r_ < 4; ++r_)
                    he[(size_t)(mt * 32 + s * 16 + lq * 4 + r_) * 64 + col] = f2b(fmaxf(a2[s][r_] + v2, 0.f));
            }
            __syncthreads();
        }
    }
}

// ---------------- mid: pn = segment-mean(hn) | ein = [prefix-mean(he) | edges], blockIdx split ----------------
__global__ __launch_bounds__(256) void k_mid(
        const ushort_t* __restrict__ hn, const ushort_t* __restrict__ he,
        const float* __restrict__ edges,
        ushort_t* __restrict__ pn, ushort_t* __restrict__ ein) {
    const int tid = threadIdx.x;
    if (blockIdx.x < 512) {
        // wave per node row: pn[ri] = mean over window of hn
        int ri = blockIdx.x * 4 + (tid >> 6);
        int l = tid & 63;
        int b = ri >> 10, i = ri & 1023;
        int t = min(i, MM);
        int base = b * NEDGE + edge_base(i);
        float s0 = 0.f, s1 = 0.f;
        for (int p = 0; p < t; ++p) {
            unsigned u = ((const unsigned*)(hn + (size_t)(base + p) * 128))[l];
            s0 += b2f((ushort_t)(u & 0xffff));
            s1 += b2f((ushort_t)(u >> 16));
        }
        float inv = 1.0f / (float)max(t, 1);
        unsigned o = (unsigned)f2b(s0 * inv) | ((unsigned)f2b(s1 * inv) << 16);
        ((unsigned*)(pn + (size_t)ri * 128))[l] = o;
    } else {
        int bi = blockIdx.x - 512;
        int b = bi >> 10, i = bi & 1023;
        int t = min(i, MM);
        if (t == 0) return;
        int base = b * NEDGE + edge_base(i);
        __shared__ alignas(16) ushort_t hw[32 * 64];
        for (int u = tid; u < t * 8; u += 256)
            ((uint4*)hw)[u] = ((const uint4*)he)[(size_t)base * 8 + u];
        __syncthreads();
        if (tid < 64) {
            float run = 0.f;
            for (int p = 0; p < t; ++p) {
                float v = (p == 0) ? 0.f : run / (float)p;
                ein[(size_t)(base + p) * 96 + tid] = f2b(v);
                run += b2f(hw[p * 64 + tid]);
            }
        } else if (tid < 96) {
            int c = tid - 64;
            for (int p = 0; p < t; ++p)
                ein[(size_t)(base + p) * 96 + 64 + c] = f2b(edges[(size_t)(base + p) * 32 + c]);
        }
    }
}

// ---------------- final: node MLP tiles ([pn|nodesb] 192->192->64) | le12 (96->96->32) ----------------
__global__ __launch_bounds__(192) void k_final(
        const ushort_t* __restrict__ pn, const ushort_t* __restrict__ nodesb,
        const ushort_t* __restrict__ pln1, const float* __restrict__ bln1,
        const ushort_t* __restrict__ pln2, const float* __restrict__ bln2,
        float* __restrict__ out_nodes,
        const ushort_t* __restrict__ ein, const ushort_t* __restrict__ ple1,
        const float* __restrict__ ble1, const ushort_t* __restrict__ ple2,
        const float* __restrict__ ble2, float* __restrict__ out_edges) {
    __shared__ alignas(16) ushort_t LA[32 * 200];
    __shared__ alignas(16) ushort_t LB[32 * 200];
    const int tid = threadIdx.x;
    const int w = tid >> 6, l = tid & 63, lrow = l & 15, lq = l >> 4;
    floatx4 zero = {0.f, 0.f, 0.f, 0.f};

    if (blockIdx.x < 64) {
        // ---- node final MLP, tile of 32 rows ----
        int tile = blockIdx.x;
        for (int u = tid; u < 768; u += 192) {        // 32 rows x 24 uint4 chunks
            int row = u / 24, c = u - row * 24;
            int ri = tile * 32 + row;
            int b = ri >> 10, i = ri & 1023;
            const uint4* src = (c < 16) ? ((const uint4*)(pn + (size_t)ri * 128) + c)
                                        : ((const uint4*)(nodesb + (size_t)(b * NN + i) * 64) + (c - 16));
            *(uint4*)&LA[row * 200 + c * 8] = *src;
        }
        bf16x8 f1[6][4]; float v1[4];
#pragma unroll
        for (int kt = 0; kt < 6; ++kt)
#pragma unroll
            for (int nt = 0; nt < 4; ++nt)
                f1[kt][nt] = *(const bf16x8*)(pln1 + (size_t)(w * 64 + nt * 16 + lrow) * 192 + kt * 32 + lq * 8);
#pragma unroll
        for (int nt = 0; nt < 4; ++nt) v1[nt] = bln1[w * 64 + nt * 16 + lrow];
        __syncthreads();

        floatx4 acc[2][4];
#pragma unroll
        for (int s = 0; s < 2; ++s)
#pragma unroll
            for (int nt = 0; nt < 4; ++nt) acc[s][nt] = zero;
#pragma unroll
        for (int s = 0; s < 2; ++s)
#pragma unroll
            for (int kt = 0; kt < 6; ++kt) {
                bf16x8 a = *(const bf16x8*)&LA[(s * 16 + lrow) * 200 + kt * 32 + lq * 8];
#pragma unroll
                for (int nt = 0; nt < 4; ++nt)
                    acc[s][nt] = __builtin_amdgcn_mfma_f32_16x16x32_bf16(a, f1[kt][nt], acc[s][nt], 0, 0, 0);
            }
#pragma unroll
        for (int s = 0; s < 2; ++s)
#pragma unroll
            for (int nt = 0; nt < 4; ++nt) {
                int col = w * 64 + nt * 16 + lrow;
#pragma unroll
                for (int r_ = 0; r_ < 4; ++r_)
                    LB[(s * 16 + lq * 4 + r_) * 200 + col] = f2b(fmaxf(acc[s][nt][r_] + v1[nt], 0.f));
            }
        __syncthreads();

        if (w < 2) {
            bf16x8 f2[6][2]; float v2[2];
#pragma unroll
            for (int kt = 0; kt < 6; ++kt)
#pragma unroll
                for (int nt = 0; nt < 2; ++nt)
                    f2[kt][nt] = *(const bf16x8*)(pln2 + (size_t)(w * 32 + nt * 16 + lrow) * 192 + kt * 32 + lq * 8);
#pragma unroll
            for (int nt = 0; nt < 2; ++nt) v2[nt] = bln2[w * 32 + nt * 16 + lrow];
            floatx4 a2[2][2];
#pragma unroll
            for (int s = 0; s < 2; ++s) { a2[s][0] = zero; a2[s][1] = zero; }
#pragma unroll
            for (int s = 0; s < 2; ++s)
#pragma unroll
                for (int kt = 0; kt < 6; ++kt) {
                    bf16x8 a = *(const bf16x8*)&LB[(s * 16 + lrow) * 200 + kt * 32 + lq * 8];
#pragma unroll
                    for (int nt = 0; nt < 2; ++nt)
                        a2[s][nt] = __builtin_amdgcn_mfma_f32_16x16x32_bf16(a, f2[kt][nt], a2[s][nt], 0, 0, 0);
                }
#pragma unroll
            for (int s = 0; s < 2; ++s)
#pragma unroll
                for (int nt = 0; nt < 2; ++nt) {
                    int col = w * 32 + nt * 16 + lrow;
#pragma unroll
                    for (int r_ = 0; r_ < 4; ++r_)
                        out_nodes[(size_t)(tile * 32 + s * 16 + lq * 4 + r_) * 64 + col] =
                            fmaxf(a2[s][nt][r_] + v2[nt], 0.f);
                }
        }
    } else {
        // ---- le12 tile (round-6 proven) ----
        int mt = blockIdx.x - 64;
        for (int k = 0; k < 11; ++k) {
            int rr = w * 11 + k;
            if (rr >= 32) break;
            unsigned* xrow = (unsigned*)(LA + rr * 104);
            const unsigned* src = (const unsigned*)(ein + (size_t)(mt * 32 + rr) * 96);
            if (l < 48) xrow[l] = src[l];
        }
        bf16x8 fb1[3][2]; float v1[2];
#pragma unroll
        for (int kt = 0; kt < 3; ++kt)
#pragma unroll
            for (int nt = 0; nt < 2; ++nt)
                fb1[kt][nt] = *(const bf16x8*)(ple1 + (size_t)(w * 32 + nt * 16 + lrow) * 96 + kt * 32 + lq * 8);
#pragma unroll
        for (int nt = 0; nt < 2; ++nt) v1[nt] = ble1[w * 32 + nt * 16 + lrow];
        bf16x8 fb2[3]; float v2 = 0.f;
        if (w < 2) {
#pragma unroll
            for (int kt = 0; kt < 3; ++kt)
                fb2[kt] = *(const bf16x8*)(ple2 + (size_t)(w * 16 + lrow) * 96 + kt * 32 + lq * 8);
            v2 = ble2[w * 16 + lrow];
        }
        __syncthreads();

        floatx4 acc[2][2];
#pragma unroll
        for (int s = 0; s < 2; ++s) { acc[s][0] = zero; acc[s][1] = zero; }
#pragma unroll
        for (int s = 0; s < 2; ++s)
#pragma unroll
            for (int kt = 0; kt < 3; ++kt) {
                bf16x8 a = *(const bf16x8*)&LA[(s * 16 + lrow) * 104 + kt * 32 + lq * 8];
#pragma unroll
                for (int nt = 0; nt < 2; ++nt)
                    acc[s][nt] = __builtin_amdgcn_mfma_f32_16x16x32_bf16(a, fb1[kt][nt], acc[s][nt], 0, 0, 0);
            }
#pragma unroll
        for (int s = 0; s < 2; ++s)
#pragma unroll
            for (int nt = 0; nt < 2; ++nt) {
                int col = w * 32 + nt * 16 + lrow;
#pragma unroll
                for (int r_ = 0; r_ < 4; ++r_)
                    LB[(s * 16 + lq * 4 + r_) * 104 + col] = f2b(fmaxf(acc[s][nt][r_] + v1[nt], 0.f));
            }
        __syncthreads();

        if (w < 2) {
            floatx4 a2[2] = {zero, zero};
#pragma unroll
            for (int s = 0; s < 2; ++s)
#pragma unroll
                for (int kt = 0; kt < 3; ++kt) {
                    bf16x8 a = *(const bf16x8*)&LB[(s * 16 + lrow) * 104 + kt * 32 + lq * 8];
                    a2[s] = __builtin_amdgcn_mfma_f32_16x16x32_bf16(a, fb2[kt], a2[s], 0, 0, 0);
                }
#pragma unroll
            for (int s = 0; s < 2; ++s) {
                int col = w * 16 + lrow;
#pragma unroll
                for (int r_ = 0; r_ < 4; ++r_)
                    out_edges[(size_t)(mt * 32 + s * 16 + lq * 4 + r_) * 32 + col] = fmaxf(a2[s][r_] + v2, 0.f);
            }
        }
    }
}

extern "C" void kernel_launch(void* const* d_in, const int* in_sizes, int n_in,
                              void* d_out, int out_size, void* d_ws, size_t ws_size,
                              hipStream_t stream) {
    const float* nodes = (const float*)d_in[0];
    const float* edges = (const float*)d_in[1];
    const float* Wan1 = (const float*)d_in[2];  const float* ban1 = (const float*)d_in[3];
    const float* Wan2 = (const float*)d_in[4];  const float* ban2 = (const float*)d_in[5];
    const float* Wln1 = (const float*)d_in[6];  const float* bln1 = (const float*)d_in[7];
    const float* Wln2 = (const float*)d_in[8];  const float* bln2 = (const float*)d_in[9];
    const float* Wae1 = (const float*)d_in[10]; const float* bae1 = (const float*)d_in[11];
    const float* Wae2 = (const float*)d_in[12]; const float* bae2 = (const float*)d_in[13];
    const float* Wle1 = (const float*)d_in[14]; const float* ble1 = (const float*)d_in[15];
    const float* Wle2 = (const float*)d_in[16]; const float* ble2 = (const float*)d_in[17];

    char* ws = (char*)d_ws;
    size_t o = 0;
    auto alloc = [&](size_t bytes) -> void* {
        void* r = ws + o;
        o += (bytes + 255) & ~(size_t)255;
        return r;
    };
    ushort_t* hn     = (ushort_t*)alloc((size_t)MROWS * 128 * 2);
    ushort_t* he     = (ushort_t*)alloc((size_t)MROWS * 64 * 2);
    ushort_t* ein    = (ushort_t*)alloc((size_t)MROWS * 96 * 2);
    ushort_t* pn     = (ushort_t*)alloc((size_t)2048 * 128 * 2);
    ushort_t* nodesb = (ushort_t*)alloc((size_t)2 * NN * 64 * 2);
    ushort_t* pan1 = (ushort_t*)alloc(160 * 256 * 2);
    ushort_t* pan2 = (ushort_t*)alloc(256 * 128 * 2);
    ushort_t* pae1 = (ushort_t*)alloc(96 * 128 * 2);
    ushort_t* pae2 = (ushort_t*)alloc(128 * 64 * 2);
    ushort_t* ple1 = (ushort_t*)alloc(96 * 96 * 2);
    ushort_t* ple2 = (ushort_t*)alloc(96 * 32 * 2);
    ushort_t* pln1 = (ushort_t*)alloc(192 * 192 * 2);
    ushort_t* pln2 = (ushort_t*)alloc(192 * 64 * 2);

    float* out_nodes = (float*)d_out;
    float* out_edges = (float*)d_out + 2 * NN * 64;

    k_pack<<<736, 256, 0, stream>>>(Wan1, Wan2, Wae1, Wae2, Wle1, Wle2, Wln1, Wln2, nodes,
                                    pan1, pan2, pae1, pae2, ple1, ple2, pln1, pln2, nodesb);
    k_agg<<<NODE_BLKS + EDGE_BLKS, 256, 0, stream>>>(nodesb, edges,
                                                     pan1, ban1, pan2, ban2,
                                                     pae1, bae1, pae2, bae2, hn, he);
    k_mid<<<2560, 256, 0, stream>>>(hn, he, edges, pn, ein);
    k_final<<<64 + 2015, 192, 0, stream>>>(pn, nodesb, pln1, bln1, pln2, bln2, out_nodes,
                                           ein, ple1, ble1, ple2, ble2, out_edges);

    (void)in_sizes; (void)n_in; (void)out_size; (void)ws_size;
}

// Round 8
// 167.493 us; speedup vs baseline: 1.1081x; 1.1081x over previous
//
#include <hip/hip_runtime.h>
#include <cstdint>

#define NN    1024
#define MM    32
#define NEDGE 32240
#define MROWS 64480   // 2*NEDGE

typedef unsigned short ushort_t;

typedef __bf16 bf16x8 __attribute__((ext_vector_type(8)));
typedef float  floatx4 __attribute__((ext_vector_type(4)));

__device__ __forceinline__ float b2f(ushort_t u) {
    union { unsigned int i; float f; } v; v.i = ((unsigned int)u) << 16; return v.f;
}
__device__ __forceinline__ ushort_t f2b(float f) {
    unsigned int u = __builtin_bit_cast(unsigned int, f);
    u = (u + 0x7FFFu + ((u >> 16) & 1u)) >> 16;
    return (ushort_t)u;
}
// K(i): number of edges before node i
__device__ __forceinline__ int edge_base(int i) {
    return (i <= MM) ? ((i * (i - 1)) >> 1) : (496 + (i - MM) * MM);
}
// edge id e -> (dest i, src j)   [validated round 3; used only in pack now]
__device__ __forceinline__ void edge_ij(int e, int& i, int& j) {
    if (e < 496) {
        i = (int)((1.0f + sqrtf(8.0f * (float)e + 1.0f)) * 0.5f);
        while (((i * (i - 1)) >> 1) > e) --i;
        while (((i * (i + 1)) >> 1) <= e) ++i;
        j = e - ((i * (i - 1)) >> 1);
    } else {
        int q = e - 496;
        i = MM + (q >> 5);
        j = i - MM + (q & 31);
    }
}

// ---------------- pack: LDS-tiled weight transpose + nodes bf16 + ein edge-cols + ij table ----------------
__global__ __launch_bounds__(256) void k_pack(
        const float* an1, const float* an2, const float* ae1, const float* ae2,
        const float* le1, const float* le2, const float* ln1, const float* ln2,
        const float* nodes, const float* edges,
        ushort_t* pan1, ushort_t* pan2, ushort_t* pae1, ushort_t* pae2,
        ushort_t* ple1, ushort_t* ple2, ushort_t* pln1, ushort_t* pln2,
        ushort_t* nodesb, ushort_t* ein, int2* ijt) {
    __shared__ float tile[32][33];
    const int bid = blockIdx.x;
    const int tid = threadIdx.x;
    if (bid < 152) {
        // 32x32 transpose tile of one weight matrix (all K,N are multiples of 32)
        const float* s; ushort_t* d; int K, N, t;
        if (bid < 40)       { s = an1; d = pan1; K = 160; N = 256; t = bid;       }
        else if (bid < 72)  { s = an2; d = pan2; K = 256; N = 128; t = bid - 40;  }
        else if (bid < 84)  { s = ae1; d = pae1; K = 96;  N = 128; t = bid - 72;  }
        else if (bid < 92)  { s = ae2; d = pae2; K = 128; N = 64;  t = bid - 84;  }
        else if (bid < 101) { s = le1; d = ple1; K = 96;  N = 96;  t = bid - 92;  }
        else if (bid < 104) { s = le2; d = ple2; K = 96;  N = 32;  t = bid - 101; }
        else if (bid < 140) { s = ln1; d = pln1; K = 192; N = 192; t = bid - 104; }
        else                { s = ln2; d = pln2; K = 192; N = 64;  t = bid - 140; }
        int ntn = N >> 5;
        int tk = t / ntn, tn = t - tk * ntn;
        int k0 = tk * 32, n0 = tn * 32;
        int tx = tid & 31, ty = tid >> 5;
#pragma unroll
        for (int m = 0; m < 4; ++m)
            tile[ty + m * 8][tx] = s[(size_t)(k0 + ty + m * 8) * N + n0 + tx];
        __syncthreads();
#pragma unroll
        for (int m = 0; m < 4; ++m)
            d[(size_t)(n0 + ty + m * 8) * K + k0 + tx] = f2b(tile[tx][ty + m * 8]);
    } else if (bid < 280) {
        // nodes fp32 -> bf16 (32768 threads exactly)
        int i4 = (bid - 152) * 256 + tid;
        float4 v = ((const float4*)nodes)[i4];
        uint2 o;
        o.x = (unsigned)f2b(v.x) | ((unsigned)f2b(v.y) << 16);
        o.y = (unsigned)f2b(v.z) | ((unsigned)f2b(v.w) << 16);
        ((uint2*)nodesb)[i4] = o;
    } else if (bid < 2295) {
        // edges fp32 -> bf16 into ein cols 64..95 (515840 threads exactly)
        int idx = (bid - 280) * 256 + tid;
        int r = idx >> 3, c4 = idx & 7;
        float4 v = ((const float4*)(edges + (size_t)r * 32))[c4];
        uint2 o;
        o.x = (unsigned)f2b(v.x) | ((unsigned)f2b(v.y) << 16);
        o.y = (unsigned)f2b(v.z) | ((unsigned)f2b(v.w) << 16);
        *(uint2*)(ein + (size_t)r * 96 + 64 + c4 * 4) = o;
    } else {
        // ij table
        int e = (bid - 2295) * 256 + tid;
        if (e < NEDGE) { int i, j; edge_ij(e, i, j); ijt[e] = make_int2(i, j); }
    }
}

// ---------------- agg: one block per 32-row tile; node tiles [0,2015), edge tiles [2015,4030) ----------------
__global__ __launch_bounds__(256, 2) void k_agg(
        const ushort_t* __restrict__ nodesb, const float* __restrict__ edges,
        const int2* __restrict__ ijt,
        const ushort_t* __restrict__ pan1, const float* __restrict__ ban1,
        const ushort_t* __restrict__ pan2, const float* __restrict__ ban2,
        const ushort_t* __restrict__ pae1, const float* __restrict__ bae1,
        const ushort_t* __restrict__ pae2, const float* __restrict__ bae2,
        ushort_t* __restrict__ hn, ushort_t* __restrict__ he) {
    __shared__ alignas(16) ushort_t L1[32 * 168];   // node: X (pitch 168) / edge: pairs (pitch 104)
    __shared__ alignas(16) ushort_t L2[32 * 264];   // node: H1n (pitch 264) / edge: H1e (pitch 136)
    const int tid = threadIdx.x;
    const int w = tid >> 6, l = tid & 63, lrow = l & 15, lq = l >> 4;
    floatx4 zero = {0.f, 0.f, 0.f, 0.f};

    if (blockIdx.x < 2015) {
        const int mt = blockIdx.x;
        // ---- gather: wave w rows w*8..w*8+7; ij loads hoisted for pipelining ----
        int2 ij[8];
#pragma unroll
        for (int k = 0; k < 8; ++k) {
            int r = mt * 32 + w * 8 + k;
            int e = (r >= NEDGE) ? r - NEDGE : r;
            ij[k] = ijt[e];
        }
#pragma unroll
        for (int k = 0; k < 8; ++k) {
            int rr = w * 8 + k;
            int r = mt * 32 + rr;
            int b = (r >= NEDGE) ? 1 : 0;
            ushort_t* xr = L1 + rr * 168;
            const unsigned* nj = (const unsigned*)(nodesb + (size_t)(b * NN + ij[k].y) * 64);
            const unsigned* ni = (const unsigned*)(nodesb + (size_t)(b * NN + ij[k].x) * 64);
            if (l < 32) { ((unsigned*)xr)[l] = nj[l]; ((unsigned*)xr)[48 + l] = ni[l]; }
            else        xr[64 + (l - 32)] = f2b(edges[(size_t)r * 32 + (l - 32)]);
        }
        {   // ---- an1: 160 -> 256, wave cols w*64..+63 (NT=4, KT=5) ----
            bf16x8 b1[5][4]; float v1[4];
#pragma unroll
            for (int kt = 0; kt < 5; ++kt)
#pragma unroll
                for (int nt = 0; nt < 4; ++nt)
                    b1[kt][nt] = *(const bf16x8*)(pan1 + (size_t)(w * 64 + nt * 16 + lrow) * 160 + kt * 32 + lq * 8);
#pragma unroll
            for (int nt = 0; nt < 4; ++nt) v1[nt] = ban1[w * 64 + nt * 16 + lrow];
            __syncthreads();
            floatx4 acc[2][4];
#pragma unroll
            for (int s = 0; s < 2; ++s)
#pragma unroll
                for (int nt = 0; nt < 4; ++nt) acc[s][nt] = zero;
#pragma unroll
            for (int s = 0; s < 2; ++s)
#pragma unroll
                for (int kt = 0; kt < 5; ++kt) {
                    bf16x8 a = *(const bf16x8*)&L1[(s * 16 + lrow) * 168 + kt * 32 + lq * 8];
#pragma unroll
                    for (int nt = 0; nt < 4; ++nt)
                        acc[s][nt] = __builtin_amdgcn_mfma_f32_16x16x32_bf16(a, b1[kt][nt], acc[s][nt], 0, 0, 0);
                }
#pragma unroll
            for (int s = 0; s < 2; ++s)
#pragma unroll
                for (int nt = 0; nt < 4; ++nt) {
                    int col = w * 64 + nt * 16 + lrow;
#pragma unroll
                    for (int r_ = 0; r_ < 4; ++r_)
                        L2[(s * 16 + lq * 4 + r_) * 264 + col] = f2b(fmaxf(acc[s][nt][r_] + v1[nt], 0.f));
                }
        }
        __syncthreads();
        {   // ---- an2: 256 -> 128, wave cols w*32..+31 (NT=2, KT=8) ----
            bf16x8 b2[8][2]; float v2[2];
#pragma unroll
            for (int kt = 0; kt < 8; ++kt)
#pragma unroll
                for (int nt = 0; nt < 2; ++nt)
                    b2[kt][nt] = *(const bf16x8*)(pan2 + (size_t)(w * 32 + nt * 16 + lrow) * 256 + kt * 32 + lq * 8);
#pragma unroll
            for (int nt = 0; nt < 2; ++nt) v2[nt] = ban2[w * 32 + nt * 16 + lrow];
            floatx4 a2[2][2];
#pragma unroll
            for (int s = 0; s < 2; ++s) { a2[s][0] = zero; a2[s][1] = zero; }
#pragma unroll
            for (int s = 0; s < 2; ++s)
#pragma unroll
                for (int kt = 0; kt < 8; ++kt) {
                    bf16x8 a = *(const bf16x8*)&L2[(s * 16 + lrow) * 264 + kt * 32 + lq * 8];
#pragma unroll
                    for (int nt = 0; nt < 2; ++nt)
                        a2[s][nt] = __builtin_amdgcn_mfma_f32_16x16x32_bf16(a, b2[kt][nt], a2[s][nt], 0, 0, 0);
                }
#pragma unroll
            for (int s = 0; s < 2; ++s)
#pragma unroll
                for (int nt = 0; nt < 2; ++nt) {
                    int col = w * 32 + nt * 16 + lrow;
#pragma unroll
                    for (int r_ = 0; r_ < 4; ++r_)
                        hn[(size_t)(mt * 32 + s * 16 + lq * 4 + r_) * 128 + col] = f2b(fmaxf(a2[s][nt][r_] + v2[nt], 0.f));
                }
        }
    } else {
        const int mt = blockIdx.x - 2015;
        // ---- gather pairs ----
        int jj[8];
#pragma unroll
        for (int k = 0; k < 8; ++k) {
            int r = mt * 32 + w * 8 + k;
            int e = (r >= NEDGE) ? r - NEDGE : r;
            jj[k] = ijt[e].y;
        }
#pragma unroll
        for (int k = 0; k < 8; ++k) {
            int rr = w * 8 + k;
            int r = mt * 32 + rr;
            int b = (r >= NEDGE) ? 1 : 0;
            ushort_t* xr = L1 + rr * 104;
            const unsigned* nj = (const unsigned*)(nodesb + (size_t)(b * NN + jj[k]) * 64);
            if (l < 32) ((unsigned*)xr)[l] = nj[l];
            else        xr[64 + (l - 32)] = f2b(edges[(size_t)r * 32 + (l - 32)]);
        }
        {   // ---- ae1: 96 -> 128, wave cols w*32..+31 (NT=2, KT=3) ----
            bf16x8 e1[3][2]; float v1[2];
#pragma unroll
            for (int kt = 0; kt < 3; ++kt)
#pragma unroll
                for (int nt = 0; nt < 2; ++nt)
                    e1[kt][nt] = *(const bf16x8*)(pae1 + (size_t)(w * 32 + nt * 16 + lrow) * 96 + kt * 32 + lq * 8);
#pragma unroll
            for (int nt = 0; nt < 2; ++nt) v1[nt] = bae1[w * 32 + nt * 16 + lrow];
            __syncthreads();
            floatx4 acc[2][2];
#pragma unroll
            for (int s = 0; s < 2; ++s) { acc[s][0] = zero; acc[s][1] = zero; }
#pragma unroll
            for (int s = 0; s < 2; ++s)
#pragma unroll
                for (int kt = 0; kt < 3; ++kt) {
                    bf16x8 a = *(const bf16x8*)&L1[(s * 16 + lrow) * 104 + kt * 32 + lq * 8];
#pragma unroll
                    for (int nt = 0; nt < 2; ++nt)
                        acc[s][nt] = __builtin_amdgcn_mfma_f32_16x16x32_bf16(a, e1[kt][nt], acc[s][nt], 0, 0, 0);
                }
#pragma unroll
            for (int s = 0; s < 2; ++s)
#pragma unroll
                for (int nt = 0; nt < 2; ++nt) {
                    int col = w * 32 + nt * 16 + lrow;
#pragma unroll
                    for (int r_ = 0; r_ < 4; ++r_)
                        L2[(s * 16 + lq * 4 + r_) * 136 + col] = f2b(fmaxf(acc[s][nt][r_] + v1[nt], 0.f));
                }
        }
        __syncthreads();
        {   // ---- ae2: 128 -> 64, wave cols w*16..+15 (NT=1, KT=4) ----
            bf16x8 e2[4];
#pragma unroll
            for (int kt = 0; kt < 4; ++kt)
                e2[kt] = *(const bf16x8*)(pae2 + (size_t)(w * 16 + lrow) * 128 + kt * 32 + lq * 8);
            float v2 = bae2[w * 16 + lrow];
            floatx4 a2[2] = {zero, zero};
#pragma unroll
            for (int s = 0; s < 2; ++s)
#pragma unroll
                for (int kt = 0; kt < 4; ++kt) {
                    bf16x8 a = *(const bf16x8*)&L2[(s * 16 + lrow) * 136 + kt * 32 + lq * 8];
                    a2[s] = __builtin_amdgcn_mfma_f32_16x16x32_bf16(a, e2[kt], a2[s], 0, 0, 0);
                }
#pragma unroll
            for (int s = 0; s < 2; ++s) {
                int col = w * 16 + lrow;
#pragma unroll
                for (int r_ = 0; r_ < 4; ++r_)
                    he[(size_t)(mt * 32 + s * 16 + lq * 4 + r_) * 64 + col] = f2b(fmaxf(a2[s][r_] + v2, 0.f));
            }
        }
    }
}

// ---------------- mid: pn = segment-mean(hn) | ein prefix cols, blockIdx split ----------------
__global__ __launch_bounds__(256) void k_mid(
        const ushort_t* __restrict__ hn, const ushort_t* __restrict__ he,
        ushort_t* __restrict__ pn, ushort_t* __restrict__ ein) {
    const int tid = threadIdx.x;
    if (blockIdx.x < 512) {
        // wave per node row: pn[ri] = mean over window of hn (dual accumulator chains)
        int ri = blockIdx.x * 4 + (tid >> 6);
        int l = tid & 63;
        int b = ri >> 10, i = ri & 1023;
        int t = min(i, MM);
        int base = b * NEDGE + edge_base(i);
        const unsigned* hp = (const unsigned*)(hn + (size_t)base * 128) + l;
        float a0 = 0.f, a1 = 0.f, c0 = 0.f, c1 = 0.f;
        int p = 0;
        for (; p + 1 < t; p += 2) {
            unsigned u = hp[(size_t)p * 64];
            unsigned v = hp[(size_t)(p + 1) * 64];
            a0 += b2f((ushort_t)(u & 0xffff)); a1 += b2f((ushort_t)(u >> 16));
            c0 += b2f((ushort_t)(v & 0xffff)); c1 += b2f((ushort_t)(v >> 16));
        }
        if (p < t) {
            unsigned u = hp[(size_t)p * 64];
            a0 += b2f((ushort_t)(u & 0xffff)); a1 += b2f((ushort_t)(u >> 16));
        }
        float inv = 1.0f / (float)max(t, 1);
        unsigned o = (unsigned)f2b((a0 + c0) * inv) | ((unsigned)f2b((a1 + c1) * inv) << 16);
        ((unsigned*)(pn + (size_t)ri * 128))[l] = o;
    } else {
        int bi = blockIdx.x - 512;
        int b = bi >> 10, i = bi & 1023;
        int t = min(i, MM);
        if (t == 0) return;
        int base = b * NEDGE + edge_base(i);
        __shared__ alignas(16) ushort_t hw[32 * 64];
        for (int u = tid; u < t * 8; u += 256)
            ((uint4*)hw)[u] = ((const uint4*)he)[(size_t)base * 8 + u];
        __syncthreads();
        if (tid < 64) {
            float run = 0.f;
            for (int p = 0; p < t; ++p) {
                float v = (p == 0) ? 0.f : run / (float)p;
                ein[(size_t)(base + p) * 96 + tid] = f2b(v);
                run += b2f(hw[p * 64 + tid]);
            }
        }
    }
}

// ---------------- final: node MLP tiles ([pn|nodesb] 192->192->64) | le12 (96->96->32) ----------------
__global__ __launch_bounds__(192) void k_final(
        const ushort_t* __restrict__ pn, const ushort_t* __restrict__ nodesb,
        const ushort_t* __restrict__ pln1, const float* __restrict__ bln1,
        const ushort_t* __restrict__ pln2, const float* __restrict__ bln2,
        float* __restrict__ out_nodes,
        const ushort_t* __restrict__ ein, const ushort_t* __restrict__ ple1,
        const float* __restrict__ ble1, const ushort_t* __restrict__ ple2,
        const float* __restrict__ ble2, float* __restrict__ out_edges) {
    __shared__ alignas(16) ushort_t LA[32 * 200];
    __shared__ alignas(16) ushort_t LB[32 * 200];
    const int tid = threadIdx.x;
    const int w = tid >> 6, l = tid & 63, lrow = l & 15, lq = l >> 4;
    floatx4 zero = {0.f, 0.f, 0.f, 0.f};

    if (blockIdx.x < 64) {
        int tile = blockIdx.x;
        for (int u = tid; u < 768; u += 192) {        // 32 rows x 24 uint4 chunks
            int row = u / 24, c = u - row * 24;
            int ri = tile * 32 + row;
            int b = ri >> 10, i = ri & 1023;
            const uint4* src = (c < 16) ? ((const uint4*)(pn + (size_t)ri * 128) + c)
                                        : ((const uint4*)(nodesb + (size_t)(b * NN + i) * 64) + (c - 16));
            *(uint4*)&LA[row * 200 + c * 8] = *src;
        }
        bf16x8 f1[6][4]; float v1[4];
#pragma unroll
        for (int kt = 0; kt < 6; ++kt)
#pragma unroll
            for (int nt = 0; nt < 4; ++nt)
                f1[kt][nt] = *(const bf16x8*)(pln1 + (size_t)(w * 64 + nt * 16 + lrow) * 192 + kt * 32 + lq * 8);
#pragma unroll
        for (int nt = 0; nt < 4; ++nt) v1[nt] = bln1[w * 64 + nt * 16 + lrow];
        __syncthreads();

        floatx4 acc[2][4];
#pragma unroll
        for (int s = 0; s < 2; ++s)
#pragma unroll
            for (int nt = 0; nt < 4; ++nt) acc[s][nt] = zero;
#pragma unroll
        for (int s = 0; s < 2; ++s)
#pragma unroll
            for (int kt = 0; kt < 6; ++kt) {
                bf16x8 a = *(const bf16x8*)&LA[(s * 16 + lrow) * 200 + kt * 32 + lq * 8];
#pragma unroll
                for (int nt = 0; nt < 4; ++nt)
                    acc[s][nt] = __builtin_amdgcn_mfma_f32_16x16x32_bf16(a, f1[kt][nt], acc[s][nt], 0, 0, 0);
            }
#pragma unroll
        for (int s = 0; s < 2; ++s)
#pragma unroll
            for (int nt = 0; nt < 4; ++nt) {
                int col = w * 64 + nt * 16 + lrow;
#pragma unroll
                for (int r_ = 0; r_ < 4; ++r_)
                    LB[(s * 16 + lq * 4 + r_) * 200 + col] = f2b(fmaxf(acc[s][nt][r_] + v1[nt], 0.f));
            }
        __syncthreads();

        if (w < 2) {
            bf16x8 f2[6][2]; float v2[2];
#pragma unroll
            for (int kt = 0; kt < 6; ++kt)
#pragma unroll
                for (int nt = 0; nt < 2; ++nt)
                    f2[kt][nt] = *(const bf16x8*)(pln2 + (size_t)(w * 32 + nt * 16 + lrow) * 192 + kt * 32 + lq * 8);
#pragma unroll
            for (int nt = 0; nt < 2; ++nt) v2[nt] = bln2[w * 32 + nt * 16 + lrow];
            floatx4 a2[2][2];
#pragma unroll
            for (int s = 0; s < 2; ++s) { a2[s][0] = zero; a2[s][1] = zero; }
#pragma unroll
            for (int s = 0; s < 2; ++s)
#pragma unroll
                for (int kt = 0; kt < 6; ++kt) {
                    bf16x8 a = *(const bf16x8*)&LB[(s * 16 + lrow) * 200 + kt * 32 + lq * 8];
#pragma unroll
                    for (int nt = 0; nt < 2; ++nt)
                        a2[s][nt] = __builtin_amdgcn_mfma_f32_16x16x32_bf16(a, f2[kt][nt], a2[s][nt], 0, 0, 0);
                }
#pragma unroll
            for (int s = 0; s < 2; ++s)
#pragma unroll
                for (int nt = 0; nt < 2; ++nt) {
                    int col = w * 32 + nt * 16 + lrow;
#pragma unroll
                    for (int r_ = 0; r_ < 4; ++r_)
                        out_nodes[(size_t)(tile * 32 + s * 16 + lq * 4 + r_) * 64 + col] =
                            fmaxf(a2[s][nt][r_] + v2[nt], 0.f);
                }
        }
    } else {
        int mt = blockIdx.x - 64;
        for (int k = 0; k < 11; ++k) {
            int rr = w * 11 + k;
            if (rr >= 32) break;
            unsigned* xrow = (unsigned*)(LA + rr * 104);
            const unsigned* src = (const unsigned*)(ein + (size_t)(mt * 32 + rr) * 96);
            if (l < 48) xrow[l] = src[l];
        }
        bf16x8 fb1[3][2]; float v1[2];
#pragma unroll
        for (int kt = 0; kt < 3; ++kt)
#pragma unroll
            for (int nt = 0; nt < 2; ++nt)
                fb1[kt][nt] = *(const bf16x8*)(ple1 + (size_t)(w * 32 + nt * 16 + lrow) * 96 + kt * 32 + lq * 8);
#pragma unroll
        for (int nt = 0; nt < 2; ++nt) v1[nt] = ble1[w * 32 + nt * 16 + lrow];
        bf16x8 fb2[3]; float v2 = 0.f;
        if (w < 2) {
#pragma unroll
            for (int kt = 0; kt < 3; ++kt)
                fb2[kt] = *(const bf16x8*)(ple2 + (size_t)(w * 16 + lrow) * 96 + kt * 32 + lq * 8);
            v2 = ble2[w * 16 + lrow];
        }
        __syncthreads();

        floatx4 acc[2][2];
#pragma unroll
        for (int s = 0; s < 2; ++s) { acc[s][0] = zero; acc[s][1] = zero; }
#pragma unroll
        for (int s = 0; s < 2; ++s)
#pragma unroll
            for (int kt = 0; kt < 3; ++kt) {
                bf16x8 a = *(const bf16x8*)&LA[(s * 16 + lrow) * 104 + kt * 32 + lq * 8];
#pragma unroll
                for (int nt = 0; nt < 2; ++nt)
                    acc[s][nt] = __builtin_amdgcn_mfma_f32_16x16x32_bf16(a, fb1[kt][nt], acc[s][nt], 0, 0, 0);
            }
#pragma unroll
        for (int s = 0; s < 2; ++s)
#pragma unroll
            for (int nt = 0; nt < 2; ++nt) {
                int col = w * 32 + nt * 16 + lrow;
#pragma unroll
                for (int r_ = 0; r_ < 4; ++r_)
                    LB[(s * 16 + lq * 4 + r_) * 104 + col] = f2b(fmaxf(acc[s][nt][r_] + v1[nt], 0.f));
            }
        __syncthreads();

        if (w < 2) {
            floatx4 a2[2] = {zero, zero};
#pragma unroll
            for (int s = 0; s < 2; ++s)
#pragma unroll
                for (int kt = 0; kt < 3; ++kt) {
                    bf16x8 a = *(const bf16x8*)&LB[(s * 16 + lrow) * 104 + kt * 32 + lq * 8];
                    a2[s] = __builtin_amdgcn_mfma_f32_16x16x32_bf16(a, fb2[kt], a2[s], 0, 0, 0);
                }
#pragma unroll
            for (int s = 0; s < 2; ++s) {
                int col = w * 16 + lrow;
#pragma unroll
                for (int r_ = 0; r_ < 4; ++r_)
                    out_edges[(size_t)(mt * 32 + s * 16 + lq * 4 + r_) * 32 + col] = fmaxf(a2[s][r_] + v2, 0.f);
            }
        }
    }
}

extern "C" void kernel_launch(void* const* d_in, const int* in_sizes, int n_in,
                              void* d_out, int out_size, void* d_ws, size_t ws_size,
                              hipStream_t stream) {
    const float* nodes = (const float*)d_in[0];
    const float* edges = (const float*)d_in[1];
    const float* Wan1 = (const float*)d_in[2];  const float* ban1 = (const float*)d_in[3];
    const float* Wan2 = (const float*)d_in[4];  const float* ban2 = (const float*)d_in[5];
    const float* Wln1 = (const float*)d_in[6];  const float* bln1 = (const float*)d_in[7];
    const float* Wln2 = (const float*)d_in[8];  const float* bln2 = (const float*)d_in[9];
    const float* Wae1 = (const float*)d_in[10]; const float* bae1 = (const float*)d_in[11];
    const float* Wae2 = (const float*)d_in[12]; const float* bae2 = (const float*)d_in[13];
    const float* Wle1 = (const float*)d_in[14]; const float* ble1 = (const float*)d_in[15];
    const float* Wle2 = (const float*)d_in[16]; const float* ble2 = (const float*)d_in[17];

    char* ws = (char*)d_ws;
    size_t o = 0;
    auto alloc = [&](size_t bytes) -> void* {
        void* r = ws + o;
        o += (bytes + 255) & ~(size_t)255;
        return r;
    };
    ushort_t* hn     = (ushort_t*)alloc((size_t)MROWS * 128 * 2);
    ushort_t* he     = (ushort_t*)alloc((size_t)MROWS * 64 * 2);
    ushort_t* ein    = (ushort_t*)alloc((size_t)MROWS * 96 * 2);
    ushort_t* pn     = (ushort_t*)alloc((size_t)2048 * 128 * 2);
    ushort_t* nodesb = (ushort_t*)alloc((size_t)2 * NN * 64 * 2);
    int2*     ijt    = (int2*)alloc((size_t)NEDGE * 8);
    ushort_t* pan1 = (ushort_t*)alloc(160 * 256 * 2);
    ushort_t* pan2 = (ushort_t*)alloc(256 * 128 * 2);
    ushort_t* pae1 = (ushort_t*)alloc(96 * 128 * 2);
    ushort_t* pae2 = (ushort_t*)alloc(128 * 64 * 2);
    ushort_t* ple1 = (ushort_t*)alloc(96 * 96 * 2);
    ushort_t* ple2 = (ushort_t*)alloc(96 * 32 * 2);
    ushort_t* pln1 = (ushort_t*)alloc(192 * 192 * 2);
    ushort_t* pln2 = (ushort_t*)alloc(192 * 64 * 2);

    float* out_nodes = (float*)d_out;
    float* out_edges = (float*)d_out + 2 * NN * 64;

    k_pack<<<2421, 256, 0, stream>>>(Wan1, Wan2, Wae1, Wae2, Wle1, Wle2, Wln1, Wln2,
                                     nodes, edges,
                                     pan1, pan2, pae1, pae2, ple1, ple2, pln1, pln2,
                                     nodesb, ein, ijt);
    k_agg<<<4030, 256, 0, stream>>>(nodesb, edges, ijt,
                                    pan1, ban1, pan2, ban2,
                                    pae1, bae1, pae2, bae2, hn, he);
    k_mid<<<2560, 256, 0, stream>>>(hn, he, pn, ein);
    k_final<<<64 + 2015, 192, 0, stream>>>(pn, nodesb, pln1, bln1, pln2, bln2, out_nodes,
                                           ein, ple1, ble1, ple2, ble2, out_edges);

    (void)in_sizes; (void)n_in; (void)out_size; (void)ws_size;
}